// Round 6
// baseline (652.310 us; speedup 1.0000x reference)
//
#include <hip/hip_runtime.h>
#include <math.h>
#include <stdint.h>
#include <stddef.h>

typedef short short8 __attribute__((ext_vector_type(8)));   // 8 x bf16 fragment
typedef float f32x4 __attribute__((ext_vector_type(4)));

#define NKT 24           // 768 / 32 K-tiles
#define ROWPB 80         // LDS tile row stride: 64 B real (32 bf16) + 16 B pad
#define NWG 1452         // 484 mt * 3 nt

// DCT basis (P=3): rows {CA,CA,CA},{CB,0,-CB},{CC,CD,CC}
#define CA 0.57735026918962576f
#define CB 0.70710678118654752f
#define CC 0.40824829046386302f
#define CD -0.81649658092772603f

// double-buffered GEMM tiles (64000 B); epilogue [72][256] f32 = 73728 B
#define LDS_A0 0u
#define LDS_A1 11520u
#define LDS_B0 23040u
#define LDS_B1 43520u
#define LDS_TOTAL 73728

// f32 -> bf16 round-to-nearest-even
static __device__ __forceinline__ unsigned short f2bf(float x) {
  union { float f; unsigned u; } v; v.f = x;
  unsigned r = v.u + 0x7fffu + ((v.u >> 16) & 1u);
  return (unsigned short)(r >> 16);
}

// ---------------------------------------------------------------------------
// R6: same verified math as R4/R5; schedule changes only.
//   - Double-buffered LDS, ONE barrier per K-step (stage kt+1 overlaps MFMA kt)
//   - Regular (cached) output stores               [write-amp A/B vs R5's NT]
//   - m204 bijective XCD swizzle: same-mt nt-triplets share an XCD's L2
// ---------------------------------------------------------------------------
__global__ __launch_bounds__(512, 4) void fused_kernel(
    const float* __restrict__ f, const float* __restrict__ W1,
    const float* __restrict__ b1, float* __restrict__ out) {
  __shared__ alignas(16) unsigned char smem[LDS_TOTAL];

  // ---- XCD-aware bijective remap (m204): contiguous logical range per XCD ----
  int bid = blockIdx.x;
  {
    const int xcd = bid & 7, loc = bid >> 3;
    const int q = NWG / 8, r = NWG & 7;               // 181, 4
    bid = (xcd < r ? xcd * (q + 1) : r * (q + 1) + (xcd - r) * q) + loc;
  }
  const int mt = bid / 3;
  const int nt = bid - mt * 3;
  const int n0 = nt * 256;
  const int tid = threadIdx.x;
  const int wv = tid >> 6;
  const int lane = tid & 63;
  const int lrow = lane & 15;        // C col within 16-col fragment
  const int kgrp = lane >> 4;        // 0..3

  const float Cm[3][3] = {{CA, CA, CA}, {CB, 0.f, -CB}, {CC, CD, CC}};

  // ---- A-staging geometry: thread = (window aw=tid>>5, feature ak=tid&31) ----
  const int aw = tid >> 5;
  const int ak = tid & 31;
  const int gwin = mt * 16 + aw;                 // 0..7743
  const int ab2 = gwin / 484;                    // image 0..15
  const int arem = gwin - ab2 * 484;
  const int abh = arem / 22;
  const int abw = arem - abh * 22;
  const float* fp[9];
#pragma unroll
  for (int p = 0; p < 3; ++p) {
    int h = abh * 3 + p; h = h > 63 ? 63 : h;    // edge padding == index clamp
#pragma unroll
    for (int q = 0; q < 3; ++q) {
      int w = abw * 3 + q; w = w > 63 ? 63 : w;
      fp[p * 3 + q] = f + ((((size_t)ab2 * 64 + h) * 64 + w) * 768 + ak);
    }
  }
  const unsigned abase0 = (unsigned)(aw * 9) * ROWPB + (unsigned)ak * 2;

  // ---- B-staging geometry: thread = (row bn=tid>>1, 16-float half bh_) ----
  const int bn = tid >> 1;
  const int bh_ = tid & 1;
  const float* gW = W1 + (size_t)(n0 + bn) * 768 + bh_ * 16;
  const unsigned bwr = (unsigned)bn * ROWPB + (unsigned)bh_ * 32;

  f32x4 acc[9][2];
#pragma unroll
  for (int i = 0; i < 9; ++i) {
    acc[i][0] = (f32x4){0.f, 0.f, 0.f, 0.f};
    acc[i][1] = (f32x4){0.f, 0.f, 0.f, 0.f};
  }

  float xr[9];
  f32x4 wr[4];
  auto loadF = [&](int kt) {
    const int off = kt * 32;
#pragma unroll
    for (int i = 0; i < 9; ++i) xr[i] = fp[i][off];
  };
  auto loadB = [&](int kt) {
    const float* p = gW + kt * 32;
#pragma unroll
    for (int i = 0; i < 4; ++i) wr[i] = *(const f32x4*)(p + i * 4);
  };
  auto dctWriteA = [&](unsigned abuf) {
    float s1[3][3];
#pragma unroll
    for (int p = 0; p < 3; ++p)
#pragma unroll
      for (int c = 0; c < 3; ++c)
        s1[p][c] = Cm[c][0] * xr[p * 3] + Cm[c][1] * xr[p * 3 + 1] + Cm[c][2] * xr[p * 3 + 2];
#pragma unroll
    for (int a = 0; a < 3; ++a)
#pragma unroll
      for (int c = 0; c < 3; ++c) {
        float t = Cm[a][0] * s1[0][c] + Cm[a][1] * s1[1][c] + Cm[a][2] * s1[2][c];
        *(unsigned short*)(smem + abuf + abase0 + (unsigned)(a * 3 + c) * ROWPB) = f2bf(t);
      }
  };
  auto writeB = [&](unsigned bbuf) {
    short8 s0, s1v;
#pragma unroll
    for (int i = 0; i < 4; ++i) {
      s0[i]      = (short)f2bf(wr[0][i]);
      s0[i + 4]  = (short)f2bf(wr[1][i]);
      s1v[i]     = (short)f2bf(wr[2][i]);
      s1v[i + 4] = (short)f2bf(wr[3][i]);
    }
    *(short8*)(smem + bbuf + bwr)      = s0;
    *(short8*)(smem + bbuf + bwr + 16) = s1v;
  };

  const unsigned aoff = (unsigned)lrow * ROWPB + (unsigned)kgrp * 16;
  const unsigned boff = (unsigned)(wv * 32 + lrow) * ROWPB + (unsigned)kgrp * 16;

  // ---- prologue: stage tile 0 into buffer 0 ----
  loadF(0);
  loadB(0);
  dctWriteA(LDS_A0);
  writeB(LDS_B0);
  __syncthreads();

  // ---- main loop: dbuf, ONE barrier per K-step ----
  for (int kt = 0; kt < NKT; ++kt) {
    const int buf = kt & 1;
    if (kt + 1 < NKT) {            // issue next tile's global loads first
      loadF(kt + 1);
      loadB(kt + 1);
    }
    const unsigned ab = buf ? LDS_A1 : LDS_A0;
    const unsigned bb = buf ? LDS_B1 : LDS_B0;
    short8 bf0 = *(const short8*)(smem + bb + boff);
    short8 bf1 = *(const short8*)(smem + bb + boff + 16u * ROWPB);
#pragma unroll
    for (int rf = 0; rf < 9; ++rf) {
      short8 af = *(const short8*)(smem + ab + aoff + (unsigned)rf * (16u * ROWPB));
      acc[rf][0] = __builtin_amdgcn_mfma_f32_16x16x32_bf16(af, bf0, acc[rf][0], 0, 0, 0);
      acc[rf][1] = __builtin_amdgcn_mfma_f32_16x16x32_bf16(af, bf1, acc[rf][1], 0, 0, 0);
    }
    if (kt + 1 < NKT) {            // stage kt+1 into the other buffer
      dctWriteA(buf ? LDS_A0 : LDS_A1);
      writeB(buf ? LDS_B0 : LDS_B1);
    }
    __syncthreads();               // writes visible; all reads of 'buf' done
  }

  // ---- epilogue: two window-half passes over a shared [72][256] tile ----
  float* ep2 = (float*)smem;
  const float bias0 = b1[n0 + wv * 32 + lrow];
  const float bias1 = b1[n0 + wv * 32 + 16 + lrow];

#pragma unroll 1
  for (int hs = 0; hs < 2; ++hs) {
    __syncthreads();               // previous readers of smem are done
    // (1) GELU -> ep2 for M-rows [hs*72, hs*72+72), this wave's 32 cols
#pragma unroll
    for (int cf = 0; cf < 2; ++cf) {
      const float bias = cf ? bias1 : bias0;
      const int colE = wv * 32 + cf * 16 + lrow;
#pragma unroll
      for (int rf = 0; rf < 9; ++rf) {
#pragma unroll
        for (int j = 0; j < 4; ++j) {
          const int r = rf * 16 + kgrp * 4 + j;   // C/D: row=(lane>>4)*4+reg
          const int lr = r - hs * 72;
          if (lr >= 0 && lr < 72) {
            float v = acc[rf][cf][j] + bias;
            float g = 0.5f * v * (1.0f + erff(v * 0.70710678118654752f));
            ep2[lr * 256 + colE] = g;
          }
        }
      }
    }
    __syncthreads();
    // (2) wave wv IDCTs window hs*8+wv; 256 B contiguous coalesced stores
    const int gw = mt * 16 + hs * 8 + wv;
    const int ib = gw / 484;
    const int rem = gw - ib * 484;
    const int bh = rem / 22;
    const int bw = rem - bh * 22;
    const float* epw = ep2 + wv * 9 * 256;
#pragma unroll
    for (int ch = 0; ch < 4; ++ch) {
      const int col = ch * 64 + lane;
      float y[3][3];
#pragma unroll
      for (int a = 0; a < 3; ++a)
#pragma unroll
        for (int c = 0; c < 3; ++c)
          y[a][c] = epw[(a * 3 + c) * 256 + col];
      float vt[3][3];                 // vt[a][q] = sum_c y[a][c] * Cm[c][q]
#pragma unroll
      for (int a = 0; a < 3; ++a)
#pragma unroll
        for (int q = 0; q < 3; ++q)
          vt[a][q] = y[a][0] * Cm[0][q] + y[a][1] * Cm[1][q] + y[a][2] * Cm[2][q];
#pragma unroll
      for (int p = 0; p < 3; ++p) {
        const int h = bh * 3 + p;
        if (h >= 64) continue;        // crop (uniform per wave)
#pragma unroll
        for (int q = 0; q < 3; ++q) {
          const int ww = bw * 3 + q;
          if (ww >= 64) continue;     // crop (uniform per wave)
          const float o = Cm[0][p] * vt[0][q] + Cm[1][p] * vt[1][q] + Cm[2][p] * vt[2][q];
          out[((((size_t)ib * 64 + h) * 64 + ww) * 768 + n0 + col)] = o;
        }
      }
    }
  }
}

// ---------------------------------------------------------------------------
extern "C" void kernel_launch(void* const* d_in, const int* in_sizes, int n_in,
                              void* d_out, int out_size, void* d_ws, size_t ws_size,
                              hipStream_t stream) {
  const float* f  = (const float*)d_in[0];
  const float* W1 = (const float*)d_in[1];
  const float* b1 = (const float*)d_in[2];
  float* out = (float*)d_out;
  (void)d_ws; (void)ws_size;   // zero-workspace design

  fused_kernel<<<dim3(NWG), dim3(512), 0, stream>>>(f, W1, b1, out);
}

// Round 7
// 426.656 us; speedup vs baseline: 1.5289x; 1.5289x over previous
//
#include <hip/hip_runtime.h>
#include <math.h>
#include <stdint.h>
#include <stddef.h>

typedef short short8 __attribute__((ext_vector_type(8)));   // 8 x bf16 fragment
typedef float f32x4 __attribute__((ext_vector_type(4)));

#define NKT 24           // 768 / 32 K-tiles
#define ROWPB 80         // LDS tile row stride: 64 B real (32 bf16) + 16 B pad
#define NWG 1452         // 484 mt * 3 nt

// DCT basis (P=3): rows {CA,CA,CA},{CB,0,-CB},{CC,CD,CC}
#define CA 0.57735026918962576f
#define CB 0.70710678118654752f
#define CC 0.40824829046386302f
#define CD -0.81649658092772603f

// double-buffered GEMM tiles (64000 B); epilogue [72][256] f32 = 73728 B
#define LDS_A0 0u
#define LDS_A1 11520u
#define LDS_B0 23040u
#define LDS_B1 43520u
#define LDS_TOTAL 73728

// f32 -> bf16 round-to-nearest-even
static __device__ __forceinline__ unsigned short f2bf(float x) {
  union { float f; unsigned u; } v; v.f = x;
  unsigned r = v.u + 0x7fffu + ((v.u >> 16) & 1u);
  return (unsigned short)(r >> 16);
}

// ---------------------------------------------------------------------------
// R7 = R6 minus the two regressions:
//   - __launch_bounds__(512,2): 256-reg budget -> no accumulator spill
//     (R6's (512,4) forced 128 regs -> spill -> 1 GB scratch writes)
//   - nontemporal output stores (R5-proven: 356 MB vs 1.01 GB)
//   Kept from R6: dbuf one-barrier K-loop (HW-proven correct), XCD swizzle.
// ---------------------------------------------------------------------------
__global__ __launch_bounds__(512, 2) void fused_kernel(
    const float* __restrict__ f, const float* __restrict__ W1,
    const float* __restrict__ b1, float* __restrict__ out) {
  __shared__ alignas(16) unsigned char smem[LDS_TOTAL];

  // ---- XCD-aware bijective remap (m204): same-mt nt-triplets share an XCD ----
  int bid = blockIdx.x;
  {
    const int xcd = bid & 7, loc = bid >> 3;
    const int q = NWG / 8, r = NWG & 7;               // 181, 4
    bid = (xcd < r ? xcd * (q + 1) : r * (q + 1) + (xcd - r) * q) + loc;
  }
  const int mt = bid / 3;
  const int nt = bid - mt * 3;
  const int n0 = nt * 256;
  const int tid = threadIdx.x;
  const int wv = tid >> 6;
  const int lane = tid & 63;
  const int lrow = lane & 15;        // C col within 16-col fragment
  const int kgrp = lane >> 4;        // 0..3

  const float Cm[3][3] = {{CA, CA, CA}, {CB, 0.f, -CB}, {CC, CD, CC}};

  // ---- A-staging geometry: thread = (window aw=tid>>5, feature ak=tid&31) ----
  const int aw = tid >> 5;
  const int ak = tid & 31;
  const int gwin = mt * 16 + aw;                 // 0..7743
  const int ab2 = gwin / 484;                    // image 0..15
  const int arem = gwin - ab2 * 484;
  const int abh = arem / 22;
  const int abw = arem - abh * 22;
  const float* fp[9];
#pragma unroll
  for (int p = 0; p < 3; ++p) {
    int h = abh * 3 + p; h = h > 63 ? 63 : h;    // edge padding == index clamp
#pragma unroll
    for (int q = 0; q < 3; ++q) {
      int w = abw * 3 + q; w = w > 63 ? 63 : w;
      fp[p * 3 + q] = f + ((((size_t)ab2 * 64 + h) * 64 + w) * 768 + ak);
    }
  }
  const unsigned abase0 = (unsigned)(aw * 9) * ROWPB + (unsigned)ak * 2;

  // ---- B-staging geometry: thread = (row bn=tid>>1, 16-float half bh_) ----
  const int bn = tid >> 1;
  const int bh_ = tid & 1;
  const float* gW = W1 + (size_t)(n0 + bn) * 768 + bh_ * 16;
  const unsigned bwr = (unsigned)bn * ROWPB + (unsigned)bh_ * 32;

  f32x4 acc[9][2];
#pragma unroll
  for (int i = 0; i < 9; ++i) {
    acc[i][0] = (f32x4){0.f, 0.f, 0.f, 0.f};
    acc[i][1] = (f32x4){0.f, 0.f, 0.f, 0.f};
  }

  float xr[9];
  f32x4 wr[4];
  auto loadF = [&](int kt) {
    const int off = kt * 32;
#pragma unroll
    for (int i = 0; i < 9; ++i) xr[i] = fp[i][off];
  };
  auto loadB = [&](int kt) {
    const float* p = gW + kt * 32;
#pragma unroll
    for (int i = 0; i < 4; ++i) wr[i] = *(const f32x4*)(p + i * 4);
  };
  auto dctWriteA = [&](unsigned abuf) {
    float s1[3][3];
#pragma unroll
    for (int p = 0; p < 3; ++p)
#pragma unroll
      for (int c = 0; c < 3; ++c)
        s1[p][c] = Cm[c][0] * xr[p * 3] + Cm[c][1] * xr[p * 3 + 1] + Cm[c][2] * xr[p * 3 + 2];
#pragma unroll
    for (int a = 0; a < 3; ++a)
#pragma unroll
      for (int c = 0; c < 3; ++c) {
        float t = Cm[a][0] * s1[0][c] + Cm[a][1] * s1[1][c] + Cm[a][2] * s1[2][c];
        *(unsigned short*)(smem + abuf + abase0 + (unsigned)(a * 3 + c) * ROWPB) = f2bf(t);
      }
  };
  auto writeB = [&](unsigned bbuf) {
    short8 s0, s1v;
#pragma unroll
    for (int i = 0; i < 4; ++i) {
      s0[i]      = (short)f2bf(wr[0][i]);
      s0[i + 4]  = (short)f2bf(wr[1][i]);
      s1v[i]     = (short)f2bf(wr[2][i]);
      s1v[i + 4] = (short)f2bf(wr[3][i]);
    }
    *(short8*)(smem + bbuf + bwr)      = s0;
    *(short8*)(smem + bbuf + bwr + 16) = s1v;
  };

  const unsigned aoff = (unsigned)lrow * ROWPB + (unsigned)kgrp * 16;
  const unsigned boff = (unsigned)(wv * 32 + lrow) * ROWPB + (unsigned)kgrp * 16;

  // ---- prologue: stage tile 0 into buffer 0 ----
  loadF(0);
  loadB(0);
  dctWriteA(LDS_A0);
  writeB(LDS_B0);
  __syncthreads();

  // ---- main loop: dbuf, ONE barrier per K-step ----
  for (int kt = 0; kt < NKT; ++kt) {
    const int buf = kt & 1;
    if (kt + 1 < NKT) {            // issue next tile's global loads first
      loadF(kt + 1);
      loadB(kt + 1);
    }
    const unsigned ab = buf ? LDS_A1 : LDS_A0;
    const unsigned bb = buf ? LDS_B1 : LDS_B0;
    short8 bf0 = *(const short8*)(smem + bb + boff);
    short8 bf1 = *(const short8*)(smem + bb + boff + 16u * ROWPB);
#pragma unroll
    for (int rf = 0; rf < 9; ++rf) {
      short8 af = *(const short8*)(smem + ab + aoff + (unsigned)rf * (16u * ROWPB));
      acc[rf][0] = __builtin_amdgcn_mfma_f32_16x16x32_bf16(af, bf0, acc[rf][0], 0, 0, 0);
      acc[rf][1] = __builtin_amdgcn_mfma_f32_16x16x32_bf16(af, bf1, acc[rf][1], 0, 0, 0);
    }
    if (kt + 1 < NKT) {            // convert + stage kt+1 into the other buffer
      dctWriteA(buf ? LDS_A0 : LDS_A1);
      writeB(buf ? LDS_B0 : LDS_B1);
    }
    __syncthreads();               // writes visible; all reads of 'buf' done
  }

  // ---- epilogue: two window-half passes over a shared [72][256] tile ----
  float* ep2 = (float*)smem;
  const float bias0 = b1[n0 + wv * 32 + lrow];
  const float bias1 = b1[n0 + wv * 32 + 16 + lrow];

#pragma unroll 1
  for (int hs = 0; hs < 2; ++hs) {
    __syncthreads();               // previous readers of smem are done
    // (1) GELU -> ep2 for M-rows [hs*72, hs*72+72), this wave's 32 cols
#pragma unroll
    for (int cf = 0; cf < 2; ++cf) {
      const float bias = cf ? bias1 : bias0;
      const int colE = wv * 32 + cf * 16 + lrow;
#pragma unroll
      for (int rf = 0; rf < 9; ++rf) {
#pragma unroll
        for (int j = 0; j < 4; ++j) {
          const int r = rf * 16 + kgrp * 4 + j;   // C/D: row=(lane>>4)*4+reg
          const int lr = r - hs * 72;
          if (lr >= 0 && lr < 72) {
            float v = acc[rf][cf][j] + bias;
            float g = 0.5f * v * (1.0f + erff(v * 0.70710678118654752f));
            ep2[lr * 256 + colE] = g;
          }
        }
      }
    }
    __syncthreads();
    // (2) wave wv IDCTs window hs*8+wv; 256 B contiguous NT stores
    const int gw = mt * 16 + hs * 8 + wv;
    const int ib = gw / 484;
    const int rem = gw - ib * 484;
    const int bh = rem / 22;
    const int bw = rem - bh * 22;
    const float* epw = ep2 + wv * 9 * 256;
#pragma unroll
    for (int ch = 0; ch < 4; ++ch) {
      const int col = ch * 64 + lane;
      float y[3][3];
#pragma unroll
      for (int a = 0; a < 3; ++a)
#pragma unroll
        for (int c = 0; c < 3; ++c)
          y[a][c] = epw[(a * 3 + c) * 256 + col];
      float vt[3][3];                 // vt[a][q] = sum_c y[a][c] * Cm[c][q]
#pragma unroll
      for (int a = 0; a < 3; ++a)
#pragma unroll
        for (int q = 0; q < 3; ++q)
          vt[a][q] = y[a][0] * Cm[0][q] + y[a][1] * Cm[1][q] + y[a][2] * Cm[2][q];
#pragma unroll
      for (int p = 0; p < 3; ++p) {
        const int h = bh * 3 + p;
        if (h >= 64) continue;        // crop (uniform per wave)
#pragma unroll
        for (int q = 0; q < 3; ++q) {
          const int ww = bw * 3 + q;
          if (ww >= 64) continue;     // crop (uniform per wave)
          const float o = Cm[0][p] * vt[0][q] + Cm[1][p] * vt[1][q] + Cm[2][p] * vt[2][q];
          __builtin_nontemporal_store(
              o, out + ((((size_t)ib * 64 + h) * 64 + ww) * 768 + n0 + col));
        }
      }
    }
  }
}

// ---------------------------------------------------------------------------
extern "C" void kernel_launch(void* const* d_in, const int* in_sizes, int n_in,
                              void* d_out, int out_size, void* d_ws, size_t ws_size,
                              hipStream_t stream) {
  const float* f  = (const float*)d_in[0];
  const float* W1 = (const float*)d_in[1];
  const float* b1 = (const float*)d_in[2];
  float* out = (float*)d_out;
  (void)d_ws; (void)ws_size;   // zero-workspace design

  fused_kernel<<<dim3(NWG), dim3(512), 0, stream>>>(f, W1, b1, out);
}